// Round 7
// baseline (465.741 us; speedup 1.0000x reference)
//
#include <hip/hip_runtime.h>
#include <hip/hip_fp16.h>
#include <math.h>

#define DD 128
#define CAP 64   // max facts per tail bucket; Poisson(10) => P(overflow) ~ 1e-30

typedef _Float16 half_t;
typedef __attribute__((ext_vector_type(8))) _Float16 half8;
typedef __attribute__((ext_vector_type(4))) float floatx4;

#define LDW 136  // 128 + 8 f16 pad: frag rows land 4 banks apart -> 2-way alias only (free)

// packed relu: x * (x > 0)  — ROCm 7.2 has no __hmax2
__device__ __forceinline__ __half2 relu2(__half2 x) {
    return __hmul2(x, __hgt2(x, __float2half2_rn(0.f)));
}

// DPP-fused add: t += dpp(t, CTRL); pure VALU, no LDS pipe.
template <int CTRL>
__device__ __forceinline__ float dpp_add(float x) {
    int y = __builtin_amdgcn_update_dpp(0, __float_as_int(x), CTRL, 0xf, 0xf, true);
    return x + __int_as_float(y);
}

// ---------------- one-time: W[k][n] f32 -> WT[n][k] f16 (4 matrices) ---------
__global__ void wt4(const float* __restrict__ W0, const float* __restrict__ W1,
                    const float* __restrict__ W2, const float* __restrict__ W3,
                    half_t* __restrict__ T0, half_t* __restrict__ T1,
                    half_t* __restrict__ T2, half_t* __restrict__ T3) {
    const float* W = blockIdx.x == 0 ? W0 : blockIdx.x == 1 ? W1 : blockIdx.x == 2 ? W2 : W3;
    half_t* T      = blockIdx.x == 0 ? T0 : blockIdx.x == 1 ? T1 : blockIdx.x == 2 ? T2 : T3;
    for (int i = threadIdx.x; i < DD * DD; i += blockDim.x) {
        int n = i >> 7, k = i & 127;
        T[i] = (half_t)W[(size_t)k * DD + n];
    }
}

// MFMA tile pass: acc over K=128 from As(row-tile) x WT(col-tile); result left
// in acc[8] (D layout: col = t*16 + (lane&15), row = w*16 + (lane>>4)*4 + i).
__device__ __forceinline__ void mfma_pass(
    const half_t* As, const half_t* WT, int w, int lane, floatx4 acc[8]) {
    int rowf = lane & 15;
    int kgrp = (lane >> 4) * 8;
#pragma unroll
    for (int t = 0; t < 8; t++) acc[t] = (floatx4){0.f, 0.f, 0.f, 0.f};
    const half_t* ap = As + (w * 16 + rowf) * LDW + kgrp;
    const half_t* bp0 = WT + rowf * LDW + kgrp;
#pragma unroll
    for (int kk = 0; kk < DD; kk += 32) {
        half8 a = *(const half8*)(ap + kk);
#pragma unroll
        for (int t = 0; t < 8; t++) {
            half8 b = *(const half8*)(bp0 + t * 16 * LDW + kk);
            acc[t] = __builtin_amdgcn_mfma_f32_16x16x32_f16(a, b, acc[t], 0, 0, 0);
        }
    }
}

// scatter acc into a [64][LDW] f16 LDS tile (scalar ds_write_b16, cheap).
__device__ __forceinline__ void acc_to_lds(const floatx4 acc[8], half_t* OutT,
                                           int w, int lane) {
    int rowf = lane & 15;
    int rbase = w * 16 + (lane >> 4) * 4;
#pragma unroll
    for (int t = 0; t < 8; t++) {
        int col = t * 16 + rowf;
#pragma unroll
        for (int i = 0; i < 4; i++) OutT[(rbase + i) * LDW + col] = (half_t)acc[t][i];
    }
}

// coalesced copy of the [64][128] f16 tile to Packed[gr*256 + halfOff + ...]
__device__ __forceinline__ void lds_to_packed(const half_t* OutT, int tileM, int M,
                                              int tid, __half* Packed, int halfOff) {
    for (int ch = tid; ch < 1024; ch += 256) {   // 64 rows x 16 chunks of 8 halves
        int row = ch >> 4, off = (ch & 15) * 8;
        int gr = tileM + row;
        if (gr < M) {
            half8 v = *(const half8*)(OutT + row * LDW + off);
            *(uint4*)(Packed + (size_t)gr * 256 + halfOff + off) = *(uint4*)&v;
        }
    }
}

// ---------------- MFMA GEMM x2, packed-f16 epilogue --------------------------
// Packed[row] = { f16(A@W1)[0..127] , f16(A@W2)[0..127] }  (512 B/row)
__global__ __launch_bounds__(256) void gemm_pack2(
    const float* __restrict__ table, int M,
    const half_t* __restrict__ WT1_g, const half_t* __restrict__ WT2_g,
    __half* __restrict__ Packed) {
    __shared__ half_t WT[DD * LDW];     // 34.8 KB (also reused as 64x136 out tile)
    __shared__ half_t As[64 * LDW];     // 17.4 KB
    int tid = threadIdx.x;
    int lane = tid & 63;
    int w = tid >> 6;
    int tileM = blockIdx.x * 64;

    // A tile -> f16 LDS
    for (int i = tid; i < 2048; i += 256) {
        int row = i >> 5, c4 = i & 31;
        int gr = tileM + row;
        float4 v = make_float4(0.f, 0.f, 0.f, 0.f);
        if (gr < M) v = *(const float4*)(table + (size_t)gr * DD + c4 * 4);
        __half2 h01 = __floats2half2_rn(v.x, v.y);
        __half2 h23 = __floats2half2_rn(v.z, v.w);
        *(uint2*)(As + row * LDW + c4 * 4) = make_uint2(*(unsigned*)&h01, *(unsigned*)&h23);
    }
    // WT <- W1
    for (int i = tid; i < 2048; i += 256) {
        int n = i >> 4, ch = i & 15;
        *(half8*)(WT + n * LDW + ch * 8) = *(const half8*)(WT1_g + n * DD + ch * 8);
    }
    __syncthreads();
    floatx4 acc[8];
    mfma_pass(As, WT, w, lane, acc);
    __syncthreads();                    // all waves done reading WT(W1)
    acc_to_lds(acc, WT, w, lane);
    __syncthreads();
    lds_to_packed(WT, tileM, M, tid, Packed, 0);
    __syncthreads();                    // copy-out done before overwriting WT
    // WT <- W2
    for (int i = tid; i < 2048; i += 256) {
        int n = i >> 4, ch = i & 15;
        *(half8*)(WT + n * LDW + ch * 8) = *(const half8*)(WT2_g + n * DD + ch * 8);
    }
    __syncthreads();
    mfma_pass(As, WT, w, lane, acc);
    __syncthreads();
    acc_to_lds(acc, WT, w, lane);
    __syncthreads();
    lds_to_packed(WT, tileM, M, tid, Packed, 128);
}

// ---------------- MFMA GEMM: Out[M x 128] = gather(A) @ W (+bias) ------------
// (only used for the tiny QB pass; direct epilogue is fine at B=512)
__global__ __launch_bounds__(256) void gemm_mfma(
    const float* __restrict__ table, const int* __restrict__ idx, int idxAdd, int M,
    const half_t* __restrict__ WT_g, const float* __restrict__ bias,
    float* __restrict__ OutF, __half* __restrict__ OutH) {
    __shared__ half_t WT[DD * LDW];
    __shared__ half_t As[64 * LDW];
    int tid = threadIdx.x;
    int lane = tid & 63;
    int w = tid >> 6;
    int rowf = lane & 15;

    for (int i = tid; i < 2048; i += 256) {
        int n = i >> 4, ch = i & 15;
        *(half8*)(WT + n * LDW + ch * 8) = *(const half8*)(WT_g + n * DD + ch * 8);
    }
    int tileM = blockIdx.x * 64;
    for (int i = tid; i < 2048; i += 256) {
        int row = i >> 5, c4 = i & 31;
        int gr = tileM + row;
        float4 v = make_float4(0.f, 0.f, 0.f, 0.f);
        if (gr < M) {
            int src = idx ? (idx[gr] + idxAdd) : gr;
            v = *(const float4*)(table + (size_t)src * DD + c4 * 4);
        }
        __half2 h01 = __floats2half2_rn(v.x, v.y);
        __half2 h23 = __floats2half2_rn(v.z, v.w);
        *(uint2*)(As + row * LDW + c4 * 4) = make_uint2(*(unsigned*)&h01, *(unsigned*)&h23);
    }
    __syncthreads();

    floatx4 acc[8];
    mfma_pass(As, WT, w, lane, acc);
    int orow = tileM + w * 16 + (lane >> 4) * 4;
#pragma unroll
    for (int t = 0; t < 8; t++) {
        int col = t * 16 + rowf;
        float bv = bias ? bias[col] : 0.f;
#pragma unroll
        for (int i = 0; i < 4; i++) {
            int gr = orow + i;
            if (gr < M) {
                float o = acc[t][i] + bv;
                if (OutF) OutF[(size_t)gr * DD + col] = o;
                if (OutH) OutH[(size_t)gr * DD + col] = __float2half(o);
            }
        }
    }
}

// ---------------- scatter into fixed-capacity buckets ------------------------
// meta.y = RB_row(= r+1, 16 bits) | b << 16
__global__ void scatter_kernel(const int* __restrict__ facts, const int* __restrict__ tail,
                               int* __restrict__ cursor, int2* __restrict__ meta, int E) {
    int e = blockIdx.x * blockDim.x + threadIdx.x;
    if (e >= E) return;
    int b = facts[e * 6 + 0];
    int n = facts[e * 6 + 1];
    int r = facts[e * 6 + 3];
    int t = tail[e];
    int slot = atomicAdd(&cursor[t], 1);
    if (slot < CAP) meta[(size_t)t * CAP + slot] = make_int2(n, (r + 1) | (b << 16));
}

// ---------------- fused alpha + aggregation, direct to output ----------------
// one wave per segment. lanes 0-31 = message role (cols 0-127 = {hWh,hrWh}),
// lanes 32-63 = alpha role (cols 128-255 = {hWs,hrWr}). lane owns 4 cols.
// Per fact: one 512-B HB row read + one 512-B RB row read + 256-B QB read.
// Alpha reduce: DPP row_shr(1,2,4,8) + row_bcast15 -> lane63 holds the alpha
// half's 32-lane sum (chain bench-verified in rounds 2-6); one __shfl(t,63)
// broadcasts it wave-wide. No per-fact shuffle cascade (round 1's bottleneck).
__global__ __launch_bounds__(256) void agg_fused(
    const __half* __restrict__ HB, const __half* __restrict__ RB,
    const __half* __restrict__ QB, const float* __restrict__ wa,
    const float* __restrict__ wa_b, const int2* __restrict__ meta,
    const int* __restrict__ cursor, float* __restrict__ out, int T) {
    int w = threadIdx.x >> 6;
    int lane = threadIdx.x & 63;
    int seg = blockIdx.x * 4 + w;
    if (seg >= T) return;
    int hf = lane >> 5;              // 0 = message, 1 = alpha
    int c = (lane & 31) * 4;
    int hoff = hf * 128 + c;
    float4 wv = *(const float4*)(wa + c);
    __half2 wa2a = __halves2half2(__float2half(wv.x), __float2half(wv.y));
    __half2 wa2b = __halves2half2(__float2half(wv.z), __float2half(wv.w));
    float wb = wa_b[0];
    int cnt = cursor[seg];
    if (cnt > CAP) cnt = CAP;
    const int2* mp = meta + (size_t)seg * CAP;
    float a0 = 0.f, a1 = 0.f, a2 = 0.f, a3 = 0.f;

#define FB(m)                                                                  \
    {                                                                          \
        int n_ = (m).x, r_ = (m).y & 0xFFFF, b_ = (m).y >> 16;                 \
        uint2 hu = *(const uint2*)(HB + (size_t)n_ * 256 + hoff);              \
        uint2 ru = *(const uint2*)(RB + (size_t)r_ * 256 + hoff);              \
        uint2 qu = *(const uint2*)(QB + (size_t)b_ * DD + c);                  \
        __half2 s2a = __hadd2(*(__half2*)&hu.x, *(__half2*)&ru.x);             \
        __half2 s2b = __hadd2(*(__half2*)&hu.y, *(__half2*)&ru.y);             \
        __half2 p2a = relu2(__hadd2(s2a, *(__half2*)&qu.x));                   \
        __half2 p2b = relu2(__hadd2(s2b, *(__half2*)&qu.y));                   \
        __half2 t2 = __hfma2(p2b, wa2b, __hmul2(p2a, wa2a));                   \
        float t = __half2float(__low2half(t2)) + __half2float(__high2half(t2));\
        t = dpp_add<0x111>(t);                                                 \
        t = dpp_add<0x112>(t);                                                 \
        t = dpp_add<0x114>(t);                                                 \
        t = dpp_add<0x118>(t);                                                 \
        t = dpp_add<0x142>(t);   /* lane63 = alpha-half 32-lane sum */         \
        float tu = __shfl(t, 63);                                              \
        float al = 1.f / (1.f + __expf(-(tu + wb)));                           \
        if (!hf) {                                                             \
            float2 fa = __half22float2(s2a);                                   \
            float2 fb = __half22float2(s2b);                                   \
            a0 = fmaf(al, fa.x, a0);                                           \
            a1 = fmaf(al, fa.y, a1);                                           \
            a2 = fmaf(al, fb.x, a2);                                           \
            a3 = fmaf(al, fb.y, a3);                                           \
        }                                                                      \
    }

    int i = 0;
    for (; i + 1 < cnt; i += 2) {
        int2 m0 = mp[i];
        int2 m1 = mp[i + 1];
        FB(m0);
        FB(m1);
    }
    if (i < cnt) {
        int2 m0 = mp[i];
        FB(m0);
    }
#undef FB

    if (!hf) *(float4*)(out + (size_t)seg * DD + c) = make_float4(a0, a1, a2, a3);
}

extern "C" void kernel_launch(void* const* d_in, const int* in_sizes, int n_in,
                              void* d_out, int out_size, void* d_ws, size_t ws_size,
                              hipStream_t stream) {
    const float* hidden    = (const float*)d_in[0];
    const float* rel_table = (const float*)d_in[1];
    const float* Ws        = (const float*)d_in[2];
    const float* Wr        = (const float*)d_in[3];
    const float* Wqr_w     = (const float*)d_in[4];
    const float* Wqr_b     = (const float*)d_in[5];
    const float* wa_w      = (const float*)d_in[6];
    const float* wa_b      = (const float*)d_in[7];
    const float* Wh        = (const float*)d_in[8];
    const int* query_rel   = (const int*)d_in[9];
    const int* facts       = (const int*)d_in[10];
    const int* tail_index  = (const int*)d_in[11];

    int N     = in_sizes[0] / DD;   // 200000
    int Rrows = in_sizes[1] / DD;   // 481
    int B     = in_sizes[9];        // 512
    int E     = in_sizes[11];       // 1000000
    int T     = in_sizes[12];       // 100000

    char* ws = (char*)d_ws;
    size_t off = 0;
    auto alloc = [&](size_t bytes) -> void* {
        void* p = ws + off;
        off += (bytes + 255) & ~(size_t)255;
        return p;
    };
    __half* HB  = (__half*)alloc((size_t)N * 256 * 2);      // 102.4 MB
    __half* RB  = (__half*)alloc((size_t)Rrows * 256 * 2);  // 246 KB
    __half* QB  = (__half*)alloc((size_t)B * DD * 2);       // 128 KB
    int* cursor = (int*)alloc((size_t)T * 4);               // 400 KB
    int2* meta  = (int2*)alloc((size_t)T * CAP * 8);        // 51.2 MB
    half_t* WsT  = (half_t*)alloc((size_t)DD * DD * 2);     // 32 KB
    half_t* WrT  = (half_t*)alloc((size_t)DD * DD * 2);
    half_t* WqrT = (half_t*)alloc((size_t)DD * DD * 2);
    half_t* WhT  = (half_t*)alloc((size_t)DD * DD * 2);

    (void)hipMemsetAsync(cursor, 0, (size_t)T * 4, stream);

    // f16 transposed weights (one tiny launch)
    wt4<<<4, 256, 0, stream>>>(Ws, Wr, Wqr_w, Wh, WsT, WrT, WqrT, WhT);

    // HB = {f16(hidden @ Wh) || f16(hidden @ Ws)}   (Wh folded via linearity)
    gemm_pack2<<<(N + 63) / 64, 256, 0, stream>>>(hidden, N, WhT, WsT, HB);
    // RB = {f16(rel_table @ Wh) || f16(rel_table @ Wr)}
    gemm_pack2<<<(Rrows + 63) / 64, 256, 0, stream>>>(rel_table, Rrows, WhT, WrT, RB);
    // QB = f16(rel_table[query_rel+1] @ Wqr_w + Wqr_b)
    gemm_mfma<<<(B + 63) / 64, 256, 0, stream>>>(rel_table, query_rel, 1, B,
                                                 WqrT, Wqr_b, nullptr, QB);

    // t-buckets (no alpha precompute needed — fused kernel computes it)
    scatter_kernel<<<(E + 255) / 256, 256, 0, stream>>>(facts, tail_index,
                                                        cursor, meta, E);

    // out[t] = sum sigmoid(wa . relu(hWs+hrWr+qWqr)) * (hWh + hrWh)
    agg_fused<<<(T + 3) / 4, 256, 0, stream>>>(HB, RB, QB, wa_w, wa_b,
                                               meta, cursor, (float*)d_out, T);
}